// Round 4
// baseline (30.374 us; speedup 1.0000x reference)
//
#include <hip/hip_runtime.h>
#include <math.h>

#define NA 512
#define NQC 8

#define NCf ((float)(90.4756 / 6.28318530717958647692))
#define A_ERF 0.70710678118654752f      // 1/sqrt(2)
#define G_COEF 0.79788456080286536f     // sqrt(2/pi)

// ---------------- pack kernel: moments -> 3 transposed float4 planes ----------------
// plane index t = qch*NA + i  (i contiguous => coalesced reads in main kernel)
__global__ void pack_kernel(const float* __restrict__ q,
                            const float* __restrict__ r,
                            const float* __restrict__ u,
                            const float* __restrict__ quad,
                            float4* __restrict__ pa,
                            float4* __restrict__ pb,
                            float4* __restrict__ pc,
                            float4* __restrict__ r4,
                            float* __restrict__ out) {
    const int idx = blockIdx.x * blockDim.x + threadIdx.x;   // 0..4095
    if (idx == 0) out[0] = 0.0f;                             // pot accumulator init
    if (idx < NA) {
        r4[idx] = make_float4(r[idx*3+0], r[idx*3+1], r[idx*3+2], 0.0f);
    }
    if (idx >= NA * NQC) return;
    const int i = idx >> 3, qch = idx & 7;                   // quad is [i][qch][3][3]
    const float* Q = quad + (size_t)idx * 9;
    const float xx = Q[0], yy = Q[4], zz = Q[8];
    const float xy = 0.5f * (Q[1] + Q[3]);
    const float xz = 0.5f * (Q[2] + Q[6]);
    const float yz = 0.5f * (Q[5] + Q[7]);
    const float tq = xx + yy + zz;
    const int t = qch * NA + i;
    pa[t] = make_float4(q[idx], tq, u[idx*3+0], u[idx*3+1]);
    pb[t] = make_float4(u[idx*3+2], xx, yy, zz);
    pc[t] = make_float4(xy, xz, yz, 0.0f);
}

// ---------------- main kernel ----------------
// grid = 512 blocks (receiver j), block = 512 threads = 8 waves.
// wave w <-> channel w; lane <-> source i (8 chunks of 64).
// All moment/r4 loads perfectly coalesced; j-moments wave-uniform.
__global__ __launch_bounds__(512)
void main_kernel(const float4* __restrict__ pa,
                 const float4* __restrict__ pb,
                 const float4* __restrict__ pc,
                 const float4* __restrict__ r4,
                 const float* __restrict__ qarr,
                 const float* __restrict__ uarr,
                 const float* __restrict__ kaparr,
                 const float* __restrict__ alparr,
                 float* __restrict__ out) {
    const int j    = blockIdx.x;
    const int tid  = threadIdx.x;
    const int w    = tid >> 6;     // wave index == channel
    const int lane = tid & 63;

    const float4 rj = r4[j];
    const float rjx = rj.x, rjy = rj.y, rjz = rj.z;

    // receiver moments for channel w (wave-uniform)
    const int tj = w * NA + j;
    const float4 sja = pa[tj], sjb = pb[tj], sjc = pc[tj];
    const float jtq = sja.y;
    const float jxx = sjb.y, jyy = sjb.z, jzz = sjb.w;
    const float jxy = sjc.x, jxz = sjc.y, jyz = sjc.z;

    float e0 = 0.f, eph = 0.f;
    float Fx = 0.f, Fy = 0.f, Fz = 0.f;
    float Hx = 0.f, Hy = 0.f, Hz = 0.f;
    float pQQ = 0.f;

    #pragma unroll 2
    for (int k = 0; k < 8; ++k) {
        const int i = k * 64 + lane;
        const float4 ri = r4[i];                      // coalesced
        const float dx = rjx - ri.x, dy = rjy - ri.y, dz = rjz - ri.z;
        float r2 = dx*dx + dy*dy + dz*dz;
        const bool diag = (i == j);
        if (diag) r2 = 1.0f;
        const float ir  = rsqrtf(r2);
        const float rr  = r2 * ir;
        const float E   = erff(A_ERF * rr);
        const float G   = G_COEF * __expf(-0.5f * r2);
        const float ir2 = ir * ir;
        const float ir4 = ir2 * ir2;
        const float g   = E * ir;
        const float GmG = G - g;
        const float nco = diag ? 0.0f : NCf;
        const float c0 = nco * g;
        const float c1 = nco * ir2 * GmG;
        const float c2 = nco * ir2 * (-3.0f*ir2*GmG - G);
        const float c3 = nco * ir2 * (15.0f*ir4*GmG + 5.0f*G*ir2 + G);
        const float c4 = nco * ir2 * (-105.0f*ir4*ir2*GmG - 35.0f*G*ir4 - 7.0f*G*ir2 - G);

        const int t = w * NA + i;
        const float4 ma = pa[t], mb = pb[t], mc = pc[t];   // coalesced 3x16B
        const float qi = ma.x, tqi = ma.y, ux = ma.z, uy = ma.w;
        const float uz = mb.x, xx = mb.y, yy = mb.z, zz = mb.w;
        const float xy = mc.x, xz = mc.y, yz = mc.z;

        const float ud  = ux*dx + uy*dy + uz*dz;
        const float Pdx = xx*dx + xy*dy + xz*dz;
        const float Pdy = xy*dx + yy*dy + yz*dz;
        const float Pdz = xz*dx + yz*dy + zz*dz;
        const float Pdd = Pdx*dx + Pdy*dy + Pdz*dz;

        const float t0 = c0 * qi;
        e0  += t0;
        eph += t0 - c1*ud + 0.5f*(c2*Pdd + c1*tqi);

        const float cH = 0.5f*(c2*(ud - tqi) - c3*Pdd);
        const float cF = cH + 0.5f*c2*ud - c1*qi;
        const float c1h = 0.5f * c1;
        Fx += cF*dx + c1*ux - c2*Pdx;
        Fy += cF*dy + c1*uy - c2*Pdy;
        Fz += cF*dz + c1*uz - c2*Pdz;
        Hx += cH*dx + c1h*ux - c2*Pdx;
        Hy += cH*dy + c1h*uy - c2*Pdy;
        Hz += cH*dz + c1h*uz - c2*Pdz;

        const float Rdx = jxx*dx + jxy*dy + jxz*dz;
        const float Rdy = jxy*dx + jyy*dy + jyz*dz;
        const float Rdz = jxz*dx + jyz*dy + jzz*dz;
        const float Rdd = Rdx*dx + Rdy*dy + Rdz*dz;
        const float dPR = Pdx*Rdx + Pdy*Rdy + Pdz*Rdz;
        const float frob = xx*jxx + yy*jyy + zz*jzz + 2.0f*(xy*jxy + xz*jxz + yz*jyz);
        pQQ += c4*(Pdd*Rdd)
             + c3*(jtq*Pdd + tqi*Rdd + 4.0f*dPR)
             + c2*(tqi*jtq + 2.0f*frob);
    }

    // ---- full in-wave reduction (64 lanes -> lane 0), per channel ----
    float acc[9] = {e0, eph, Fx, Fy, Fz, Hx, Hy, Hz, pQQ};
    #pragma unroll
    for (int off = 1; off < 64; off <<= 1) {
        #pragma unroll
        for (int c = 0; c < 9; ++c) acc[c] += __shfl_xor(acc[c], off, 64);
    }

    __shared__ float pl[8];
    if (lane == 0) {
        const float te0 = acc[0], teph = acc[1];
        const float tFx = acc[2], tFy = acc[3], tFz = acc[4];
        const float tHx = acc[5], tHy = acc[6], tHz = acc[7];
        const float tQQ = acc[8] * 0.125f;
        const int jq = j * NQC + w;
        const float qj  = qarr[jq];
        const float ujx = uarr[jq*3+0], ujy = uarr[jq*3+1], ujz = uarr[jq*3+2];
        const float kapv = kaparr[jq];
        const float alpv = alparr[jq];

        pl[w] = qj * (teph - 0.5f*te0)
              - (ujx*tHx + ujy*tHy + ujz*tHz)
              + tQQ
              - 0.5f * kapv * teph * teph
              - 0.5f * alpv * (tFx*tFx + tFy*tFy + tFz*tFz);

        out[1 + jq] = -kapv * teph;
        out[1 + NA*NQC + jq*3 + 0] = alpv * tFx;
        out[1 + NA*NQC + jq*3 + 1] = alpv * tFy;
        out[1 + NA*NQC + jq*3 + 2] = alpv * tFz;
    }
    __syncthreads();
    if (tid == 0) {
        float s = 0.f;
        #pragma unroll
        for (int c = 0; c < 8; ++c) s += pl[c];
        atomicAdd(out, s);
    }
}

extern "C" void kernel_launch(void* const* d_in, const int* in_sizes, int n_in,
                              void* d_out, int out_size, void* d_ws, size_t ws_size,
                              hipStream_t stream) {
    const float* q    = (const float*)d_in[0];
    const float* r    = (const float*)d_in[1];
    const float* u    = (const float*)d_in[4];
    const float* quad = (const float*)d_in[5];
    const float* kap  = (const float*)d_in[6];
    const float* alp  = (const float*)d_in[7];
    float* out = (float*)d_out;
    float* ws  = (float*)d_ws;

    const size_t plane = (size_t)NA * NQC;   // float4 count per plane (4096)
    float4* pa = (float4*)ws;
    float4* pb = pa + plane;
    float4* pc = pb + plane;
    float4* r4 = pc + plane;
    (void)ws_size; (void)in_sizes; (void)n_in; (void)out_size;

    pack_kernel<<<16, 256, 0, stream>>>(q, r, u, quad, pa, pb, pc, r4, out);
    main_kernel<<<NA, 512, 0, stream>>>(pa, pb, pc, r4, q, u, kap, alp, out);
}

// Round 5
// 29.206 us; speedup vs baseline: 1.0400x; 1.0400x over previous
//
#include <hip/hip_runtime.h>
#include <math.h>

#define NA 512
#define NQC 8

#define NCf ((float)(90.4756 / 6.28318530717958647692))
#define A_ERF 0.70710678118654752f      // 1/sqrt(2)
#define G_COEF 0.79788456080286536f     // sqrt(2/pi)

// ---------------- pack kernel: moments -> 3 transposed float4 planes ----------------
// plane index t = qch*NA + i  (i contiguous => coalesced reads in main kernel)
__global__ void pack_kernel(const float* __restrict__ q,
                            const float* __restrict__ r,
                            const float* __restrict__ u,
                            const float* __restrict__ quad,
                            float4* __restrict__ pa,
                            float4* __restrict__ pb,
                            float4* __restrict__ pc,
                            float4* __restrict__ r4,
                            float* __restrict__ out) {
    const int idx = blockIdx.x * blockDim.x + threadIdx.x;   // 0..4095
    if (idx == 0) out[0] = 0.0f;                             // pot accumulator init
    if (idx < NA) {
        r4[idx] = make_float4(r[idx*3+0], r[idx*3+1], r[idx*3+2], 0.0f);
    }
    if (idx >= NA * NQC) return;
    const int i = idx >> 3, qch = idx & 7;                   // quad is [i][qch][3][3]
    const float* Q = quad + (size_t)idx * 9;
    const float xx = Q[0], yy = Q[4], zz = Q[8];
    const float xy = 0.5f * (Q[1] + Q[3]);
    const float xz = 0.5f * (Q[2] + Q[6]);
    const float yz = 0.5f * (Q[5] + Q[7]);
    const float tq = xx + yy + zz;
    const int t = qch * NA + i;
    pa[t] = make_float4(q[idx], tq, u[idx*3+0], u[idx*3+1]);
    pb[t] = make_float4(u[idx*3+2], xx, yy, zz);
    pc[t] = make_float4(xy, xz, yz, 0.0f);
}

// ---------------- main kernel ----------------
// grid = 512 blocks (receiver j), block = 512 threads = 8 waves.
// wave w <-> channel w; lane <-> source i (8 chunks of 64).
// erf via branch-free A&S 7.1.26 reusing exp(-r^2/2) (libm erff is branchy
// and divergent -> serialized exec-mask paths; this is 1 rcp + 5 FMA).
__global__ __launch_bounds__(512)
void main_kernel(const float4* __restrict__ pa,
                 const float4* __restrict__ pb,
                 const float4* __restrict__ pc,
                 const float4* __restrict__ r4,
                 const float* __restrict__ qarr,
                 const float* __restrict__ uarr,
                 const float* __restrict__ kaparr,
                 const float* __restrict__ alparr,
                 float* __restrict__ out) {
    const int j    = blockIdx.x;
    const int tid  = threadIdx.x;
    const int w    = tid >> 6;     // wave index == channel
    const int lane = tid & 63;

    const float4 rj = r4[j];
    const float rjx = rj.x, rjy = rj.y, rjz = rj.z;

    // receiver moments for channel w (wave-uniform)
    const int tj = w * NA + j;
    const float4 sja = pa[tj], sjb = pb[tj], sjc = pc[tj];
    const float jtq = sja.y;
    const float jxx = sjb.y, jyy = sjb.z, jzz = sjb.w;
    const float jxy = sjc.x, jxz = sjc.y, jyz = sjc.z;

    float e0 = 0.f, eph = 0.f;
    float Fx = 0.f, Fy = 0.f, Fz = 0.f;
    float Hx = 0.f, Hy = 0.f, Hz = 0.f;
    float pQQ = 0.f;

    #pragma unroll 2
    for (int k = 0; k < 8; ++k) {
        const int i = k * 64 + lane;
        const float4 ri = r4[i];                      // coalesced
        const float dx = rjx - ri.x, dy = rjy - ri.y, dz = rjz - ri.z;
        float r2 = dx*dx + dy*dy + dz*dz;
        const bool diag = (i == j);
        if (diag) r2 = 1.0f;
        const float ir  = rsqrtf(r2);
        const float rr  = r2 * ir;
        // ---- branch-free erf(rr/sqrt(2)) : A&S 7.1.26, exp factor shared with G ----
        const float x   = A_ERF * rr;
        const float E2  = __expf(-0.5f * r2);         // == exp(-x*x)
        const float G   = G_COEF * E2;
        const float t   = __builtin_amdgcn_rcpf(fmaf(0.3275911f, x, 1.0f));
        const float pol = t*(0.254829592f + t*(-0.284496736f + t*(1.421413741f
                         + t*(-1.453152027f + t*1.061405429f))));
        const float E   = fmaf(-pol, E2, 1.0f);
        const float ir2 = ir * ir;
        const float ir4 = ir2 * ir2;
        const float g   = E * ir;
        const float GmG = G - g;
        const float nco = diag ? 0.0f : NCf;
        const float c0 = nco * g;
        const float c1 = nco * ir2 * GmG;
        const float c2 = nco * ir2 * (-3.0f*ir2*GmG - G);
        const float c3 = nco * ir2 * (15.0f*ir4*GmG + 5.0f*G*ir2 + G);
        const float c4 = nco * ir2 * (-105.0f*ir4*ir2*GmG - 35.0f*G*ir4 - 7.0f*G*ir2 - G);

        const int tix = w * NA + i;
        const float4 ma = pa[tix], mb = pb[tix], mc = pc[tix];   // coalesced 3x16B
        const float qi = ma.x, tqi = ma.y, ux = ma.z, uy = ma.w;
        const float uz = mb.x, xx = mb.y, yy = mb.z, zz = mb.w;
        const float xy = mc.x, xz = mc.y, yz = mc.z;

        const float ud  = ux*dx + uy*dy + uz*dz;
        const float Pdx = xx*dx + xy*dy + xz*dz;
        const float Pdy = xy*dx + yy*dy + yz*dz;
        const float Pdz = xz*dx + yz*dy + zz*dz;
        const float Pdd = Pdx*dx + Pdy*dy + Pdz*dz;

        const float t0 = c0 * qi;
        e0  += t0;
        eph += t0 - c1*ud + 0.5f*(c2*Pdd + c1*tqi);

        const float cH = 0.5f*(c2*(ud - tqi) - c3*Pdd);
        const float cF = cH + 0.5f*c2*ud - c1*qi;
        const float c1h = 0.5f * c1;
        Fx += cF*dx + c1*ux - c2*Pdx;
        Fy += cF*dy + c1*uy - c2*Pdy;
        Fz += cF*dz + c1*uz - c2*Pdz;
        Hx += cH*dx + c1h*ux - c2*Pdx;
        Hy += cH*dy + c1h*uy - c2*Pdy;
        Hz += cH*dz + c1h*uz - c2*Pdz;

        const float Rdx = jxx*dx + jxy*dy + jxz*dz;
        const float Rdy = jxy*dx + jyy*dy + jyz*dz;
        const float Rdz = jxz*dx + jyz*dy + jzz*dz;
        const float Rdd = Rdx*dx + Rdy*dy + Rdz*dz;
        const float dPR = Pdx*Rdx + Pdy*Rdy + Pdz*Rdz;
        const float frob = xx*jxx + yy*jyy + zz*jzz + 2.0f*(xy*jxy + xz*jxz + yz*jyz);
        pQQ += c4*(Pdd*Rdd)
             + c3*(jtq*Pdd + tqi*Rdd + 4.0f*dPR)
             + c2*(tqi*jtq + 2.0f*frob);
    }

    // ---- full in-wave reduction (64 lanes -> lane 0), per channel ----
    float acc[9] = {e0, eph, Fx, Fy, Fz, Hx, Hy, Hz, pQQ};
    #pragma unroll
    for (int off = 1; off < 64; off <<= 1) {
        #pragma unroll
        for (int c = 0; c < 9; ++c) acc[c] += __shfl_xor(acc[c], off, 64);
    }

    __shared__ float pl[8];
    if (lane == 0) {
        const float te0 = acc[0], teph = acc[1];
        const float tFx = acc[2], tFy = acc[3], tFz = acc[4];
        const float tHx = acc[5], tHy = acc[6], tHz = acc[7];
        const float tQQ = acc[8] * 0.125f;
        const int jq = j * NQC + w;
        const float qj  = qarr[jq];
        const float ujx = uarr[jq*3+0], ujy = uarr[jq*3+1], ujz = uarr[jq*3+2];
        const float kapv = kaparr[jq];
        const float alpv = alparr[jq];

        pl[w] = qj * (teph - 0.5f*te0)
              - (ujx*tHx + ujy*tHy + ujz*tHz)
              + tQQ
              - 0.5f * kapv * teph * teph
              - 0.5f * alpv * (tFx*tFx + tFy*tFy + tFz*tFz);

        out[1 + jq] = -kapv * teph;
        out[1 + NA*NQC + jq*3 + 0] = alpv * tFx;
        out[1 + NA*NQC + jq*3 + 1] = alpv * tFy;
        out[1 + NA*NQC + jq*3 + 2] = alpv * tFz;
    }
    __syncthreads();
    if (tid == 0) {
        float s = 0.f;
        #pragma unroll
        for (int c = 0; c < 8; ++c) s += pl[c];
        atomicAdd(out, s);
    }
}

extern "C" void kernel_launch(void* const* d_in, const int* in_sizes, int n_in,
                              void* d_out, int out_size, void* d_ws, size_t ws_size,
                              hipStream_t stream) {
    const float* q    = (const float*)d_in[0];
    const float* r    = (const float*)d_in[1];
    const float* u    = (const float*)d_in[4];
    const float* quad = (const float*)d_in[5];
    const float* kap  = (const float*)d_in[6];
    const float* alp  = (const float*)d_in[7];
    float* out = (float*)d_out;
    float* ws  = (float*)d_ws;

    const size_t plane = (size_t)NA * NQC;   // float4 count per plane (4096)
    float4* pa = (float4*)ws;
    float4* pb = pa + plane;
    float4* pc = pb + plane;
    float4* r4 = pc + plane;
    (void)ws_size; (void)in_sizes; (void)n_in; (void)out_size;

    pack_kernel<<<16, 256, 0, stream>>>(q, r, u, quad, pa, pb, pc, r4, out);
    main_kernel<<<NA, 512, 0, stream>>>(pa, pb, pc, r4, q, u, kap, alp, out);
}